// Round 4
// baseline (257.625 us; speedup 1.0000x reference)
//
#include <hip/hip_runtime.h>
#include <math.h>

#define NB 2
#define NL 256
#define DM 512
#define NH 8
#define DQ 64

// ---------------------------------------------------------------------------
// K1: QKV projection GEMM. 32x64 tile, K-tile 32, thread tile 2x4.
// ---------------------------------------------------------------------------
__global__ __launch_bounds__(256) void qkv_gemm(
    const float* __restrict__ xq, const float* __restrict__ xk,
    const float* __restrict__ xv,
    const float* __restrict__ Wq, const float* __restrict__ Wk,
    const float* __restrict__ Wv,
    const float* __restrict__ bq, const float* __restrict__ bk,
    const float* __restrict__ bv,
    float* __restrict__ q, float* __restrict__ k, float* __restrict__ v)
{
    int z = blockIdx.z;
    const float* X = (z == 0) ? xq : (z == 1) ? xk : xv;
    const float* W = (z == 0) ? Wq : (z == 1) ? Wk : Wv;
    const float* bias = (z == 0) ? bq : (z == 1) ? bk : bv;
    float* O = (z == 0) ? q : (z == 1) ? k : v;

    __shared__ float As[32][33];
    __shared__ float Bs[32][68];

    int tid = threadIdx.x;
    int tx = tid & 15, ty = tid >> 4;
    int m0 = blockIdx.y * 32, n0 = blockIdx.x * 64;

    float acc[2][4] = {};

    for (int k0 = 0; k0 < 512; k0 += 32) {
        {
            int r = tid >> 3, c4 = (tid & 7) * 4;
            const float4 av = *(const float4*)(X + (m0 + r) * 512 + k0 + c4);
            As[c4 + 0][r] = av.x; As[c4 + 1][r] = av.y;
            As[c4 + 2][r] = av.z; As[c4 + 3][r] = av.w;
        }
        {
            int r = tid >> 4, c4 = (tid & 15) * 4;
            float4 b0 = *(const float4*)(W + (k0 + r) * 512 + n0 + c4);
            float4 b1 = *(const float4*)(W + (k0 + r + 16) * 512 + n0 + c4);
            *(float4*)&Bs[r][c4] = b0;
            *(float4*)&Bs[r + 16][c4] = b1;
        }
        __syncthreads();
        #pragma unroll
        for (int kk = 0; kk < 32; kk++) {
            float a0 = As[kk][ty * 2 + 0];
            float a1 = As[kk][ty * 2 + 1];
            float4 bb = *(const float4*)&Bs[kk][tx * 4];
            acc[0][0] += a0 * bb.x; acc[0][1] += a0 * bb.y;
            acc[0][2] += a0 * bb.z; acc[0][3] += a0 * bb.w;
            acc[1][0] += a1 * bb.x; acc[1][1] += a1 * bb.y;
            acc[1][2] += a1 * bb.z; acc[1][3] += a1 * bb.w;
        }
        __syncthreads();
    }

    #pragma unroll
    for (int i = 0; i < 2; i++) {
        int m = m0 + ty * 2 + i;
        int b = m >> 8, l = m & 255;
        #pragma unroll
        for (int j = 0; j < 4; j++) {
            int n = n0 + tx * 4 + j;
            int h = n >> 6, d = n & 63;
            O[((b * NH + h) * NL + l) * DQ + d] = acc[i][j] + bias[n];
        }
    }
}

// ---------------------------------------------------------------------------
// K2: fused attn softmax + u precompute. blockIdx.x<256 -> attn row, else u.
// ---------------------------------------------------------------------------
__global__ __launch_bounds__(256) void attn_u_kernel(
    const float* __restrict__ q, const float* __restrict__ k,
    const float* __restrict__ mask, float* __restrict__ attn_o,
    const float* __restrict__ v, const float* __restrict__ Wre,
    const float* __restrict__ Wim, float2* __restrict__ u)
{
    int h = blockIdx.y, b = blockIdx.z;
    int tid = threadIdx.x;
    __shared__ float smem[264];

    if (blockIdx.x < 256) {
        int qi = blockIdx.x;
        int wv = tid >> 6, lane = tid & 63;
        float* qrow = smem;
        float* wred = smem + 256;
        float* wsum = smem + 260;

        if (tid < 16)
            ((float4*)qrow)[tid] = ((const float4*)(q + ((b * NH + h) * NL + qi) * DQ))[tid];
        __syncthreads();

        const float4* kp = (const float4*)(k + ((b * NH + h) * NL + tid) * DQ);
        float acc = 0.f;
        #pragma unroll
        for (int d4 = 0; d4 < 16; d4++) {
            float4 kv = kp[d4];
            float4 qv = ((const float4*)qrow)[d4];
            acc += qv.x * kv.x + qv.y * kv.y + qv.z * kv.z + qv.w * kv.w;
        }
        acc *= 0.125f;

        float mv = mask[(b * NL + qi) * NL + tid];
        acc -= (mv == 1.0f) ? INFINITY : mv;

        float mx = acc;
        #pragma unroll
        for (int o = 32; o; o >>= 1) mx = fmaxf(mx, __shfl_xor(mx, o, 64));
        if (lane == 0) wred[wv] = mx;
        __syncthreads();
        mx = fmaxf(fmaxf(wred[0], wred[1]), fmaxf(wred[2], wred[3]));

        float e = __expf(acc - mx);
        float s = e;
        #pragma unroll
        for (int o = 32; o; o >>= 1) s += __shfl_xor(s, o, 64);
        if (lane == 0) wsum[wv] = s;
        __syncthreads();
        s = wsum[0] + wsum[1] + wsum[2] + wsum[3];

        attn_o[((b * NH + h) * NL + qi) * NL + tid] = e * __builtin_amdgcn_rcpf(s);
    } else {
        int xi = blockIdx.x - 256;          // 0..63
        int e = tid & 63, tq = tid >> 6;
        int t = xi * 4 + tq;
        float (*vrow)[64] = (float (*)[64])smem;

        const float* vp = v + ((b * NH + h) * NL + t) * DQ;
        vrow[tq][e] = vp[e];
        __syncthreads();

        const float* wr = Wre + h * 4096 + e;
        const float* wi = Wim + h * 4096 + e;
        float ar = 0.f, ai = 0.f;
        #pragma unroll
        for (int d = 0; d < 64; d++) {
            float vv = vrow[tq][d];
            ar += vv * wr[d * 64];
            ai += vv * wi[d * 64];
        }
        u[((b * NH + h) * NL + t) * DQ + e] = make_float2(ar, ai);
    }
}

// ---------------------------------------------------------------------------
// K3: EUNN recurrence. One wave per (b,h,q); lane = complex state elem d.
// The two Givens layers are fused into one 4-neighbor gather:
//   new[d] = k0*h[d] + k1*h[n1] + k2*h[n2] + k3*h[n3]   (k0 real)
// Derivation (verified against the two-stage form that passed in R2/R3):
//  even d: n={d-2,d-1,d+1}, jm=(d/2+31)&31:
//   P = s1(jm) e^{-i phi1(jm)}
//   k1 = P * s0(jm) e^{-i phi0(jm)}; k2 = P*c0(jm); k0 = c1(jm)*c0(d/2);
//   k3 = -c1(jm)*s0(d/2) e^{+i phi0(d/2)}
//  odd d: n={d-1,d+1,d+2}, j0=d>>1, jp=(j0+1)&31:
//   k1 = c1(j0) s0(j0) e^{-i phi0(j0)}; k0 = c1(j0) c0(j0);
//   Q = s1(j0) e^{+i phi1(j0)}; k2 = -Q c0(jp); k3 = Q s0(jp) e^{+i phi0(jp)}
// u is staged through LDS in 32-step double-buffered chunks so the serial
// chain never waits on a global load.
// ---------------------------------------------------------------------------
__global__ __launch_bounds__(256) void rnn_kernel(
    const float* __restrict__ attn_f, const float2* __restrict__ u,
    const float* __restrict__ theta, const float* __restrict__ phi,
    const float* __restrict__ rnn_bias, float* __restrict__ rnn_out)
{
    int tid = threadIdx.x;
    int wv = tid >> 6, d = tid & 63;
    int w = blockIdx.x * 4 + wv;
    int qi = w & 255, h = (w >> 8) & 7, b = w >> 11;

    const float* tb = theta + h * 64;
    const float* pb = phi + h * 64;

    int j0 = d >> 1;
    float k0r, k1r, k1i, k2r, k2i, k3r, k3i;
    int n1, n2, n3;
    {
        float th0 = tb[j0], ph0 = pb[j0];
        float c0 = cosf(th0), s0 = sinf(th0);
        float cp0 = cosf(ph0), sp0 = sinf(ph0);
        if ((d & 1) == 0) {
            int jm = (j0 + 31) & 31;
            float c0p = cosf(tb[jm]), s0p = sinf(tb[jm]);
            float cpp = cosf(pb[jm]), spp = sinf(pb[jm]);
            float c1 = cosf(tb[32 + jm]), s1 = sinf(tb[32 + jm]);
            float Pr = s1 * cosf(pb[32 + jm]), Pi = -s1 * sinf(pb[32 + jm]);
            float er = s0p * cpp, ei = -s0p * spp;
            k1r = Pr * er - Pi * ei; k1i = Pr * ei + Pi * er;   // h[d-2]
            k2r = Pr * c0p;          k2i = Pi * c0p;             // h[d-1]
            k0r = c1 * c0;                                       // h[d]
            k3r = -c1 * s0 * cp0;    k3i = -c1 * s0 * sp0;       // h[d+1]
            n1 = (d + 62) & 63; n2 = (d + 63) & 63; n3 = (d + 1) & 63;
        } else {
            int jp = (j0 + 1) & 31;
            float c0p = cosf(tb[jp]), s0p = sinf(tb[jp]);
            float cpp = cosf(pb[jp]), spp = sinf(pb[jp]);
            float c1 = cosf(tb[32 + j0]), s1 = sinf(tb[32 + j0]);
            k1r = c1 * s0 * cp0;     k1i = -c1 * s0 * sp0;       // h[d-1]
            k0r = c1 * c0;                                       // h[d]
            float Qr = s1 * cosf(pb[32 + j0]), Qi = s1 * sinf(pb[32 + j0]);
            k2r = -Qr * c0p;         k2i = -Qi * c0p;            // h[d+1]
            float er = s0p * cpp, ei = s0p * spp;
            k3r = Qr * er - Qi * ei; k3i = Qr * ei + Qi * er;    // h[d+2]
            n1 = (d + 63) & 63; n2 = (d + 1) & 63; n3 = (d + 2) & 63;
        }
    }
    float bias_d = rnn_bias[h * 64 + d];

    __shared__ float arow[4][256];
    __shared__ float4 ubuf[2][1024];   // 2 x 16KB chunks (32 steps x 64 float2)

    const float* ap = attn_f + (size_t)w * 256;
    #pragma unroll
    for (int i = 0; i < 4; i++) arow[wv][d + i * 64] = ap[d + i * 64];

    const float4* usrc = (const float4*)(u + (size_t)((b * NH + h) * NL) * DQ);
    {
        float4 r0[4];
        #pragma unroll
        for (int i = 0; i < 4; i++) r0[i] = usrc[tid + 256 * i];
        #pragma unroll
        for (int i = 0; i < 4; i++) ubuf[0][tid + 256 * i] = r0[i];
    }
    __syncthreads();

    float hr = 0.f, hi = 0.f;
    int cur = 0;
    for (int ch = 0; ch < 8; ch++) {
        float4 rn[4];
        if (ch < 7) {   // issue next chunk's loads; ~32 steps of compute to land
            #pragma unroll
            for (int i = 0; i < 4; i++) rn[i] = usrc[(ch + 1) * 1024 + tid + 256 * i];
        }
        const float2* uld = (const float2*)ubuf[cur];
        const float* arc = &arow[wv][ch * 32];
        #pragma unroll 8
        for (int tt = 0; tt < 32; tt++) {
            float2 uu = uld[tt * 64 + d];
            float a_t = arc[tt];
            // one independent gather stage (6 bpermutes)
            float g1r = __shfl(hr, n1, 64), g1i = __shfl(hi, n1, 64);
            float g2r = __shfl(hr, n2, 64), g2i = __shfl(hi, n2, 64);
            float g3r = __shfl(hr, n3, 64), g3i = __shfl(hi, n3, 64);
            float zr = a_t * uu.x + k0r * hr;
            float zi = a_t * uu.y + k0r * hi;
            zr += k1r * g1r - k1i * g1i;
            zi += k1r * g1i + k1i * g1r;
            zr += k2r * g2r - k2i * g2i;
            zi += k2r * g2i + k2i * g2r;
            zr += k3r * g3r - k3i * g3i;
            zi += k3r * g3i + k3i * g3r;
            float mm = zr * zr + zi * zi;
            float m = __builtin_amdgcn_sqrtf(mm);
            float sc = fmaxf(m + bias_d, 0.f) * __builtin_amdgcn_rcpf(m + 1e-5f);
            hr = zr * sc;
            hi = zi * sc;
        }
        __syncthreads();
        if (ch < 7) {
            #pragma unroll
            for (int i = 0; i < 4; i++) ubuf[cur ^ 1][tid + 256 * i] = rn[i];
        }
        __syncthreads();
        cur ^= 1;
    }

    rnn_out[(b * NL + qi) * DM + h * DQ + d] = hr;
}

// ---------------------------------------------------------------------------
// K4: output projection. 16x64 tile, K-tile 32.
// ---------------------------------------------------------------------------
__global__ __launch_bounds__(256) void out_gemm(
    const float* __restrict__ A, const float* __restrict__ W,
    const float* __restrict__ bias, float* __restrict__ C)
{
    __shared__ float As[32][17];
    __shared__ float Bs[32][68];

    int tid = threadIdx.x;
    int tx = tid & 15, ty = tid >> 4;
    int m0 = blockIdx.y * 16, n0 = blockIdx.x * 64;

    float acc[4] = {};

    for (int k0 = 0; k0 < 512; k0 += 32) {
        {
            int r = tid >> 4, c2 = (tid & 15) * 2;
            const float2 av = *(const float2*)(A + (m0 + r) * 512 + k0 + c2);
            As[c2 + 0][r] = av.x; As[c2 + 1][r] = av.y;
        }
        {
            int r = tid >> 4, c4 = (tid & 15) * 4;
            float4 b0 = *(const float4*)(W + (k0 + r) * 512 + n0 + c4);
            float4 b1 = *(const float4*)(W + (k0 + r + 16) * 512 + n0 + c4);
            *(float4*)&Bs[r][c4] = b0;
            *(float4*)&Bs[r + 16][c4] = b1;
        }
        __syncthreads();
        #pragma unroll
        for (int kk = 0; kk < 32; kk++) {
            float a = As[kk][ty];
            float4 bb = *(const float4*)&Bs[kk][tx * 4];
            acc[0] += a * bb.x; acc[1] += a * bb.y;
            acc[2] += a * bb.z; acc[3] += a * bb.w;
        }
        __syncthreads();
    }

    int m = m0 + ty;
    #pragma unroll
    for (int j = 0; j < 4; j++) {
        int n = n0 + tx * 4 + j;
        C[m * 512 + n] = acc[j] + bias[n];
    }
}

// ---------------------------------------------------------------------------
extern "C" void kernel_launch(void* const* d_in, const int* in_sizes, int n_in,
                              void* d_out, int out_size, void* d_ws, size_t ws_size,
                              hipStream_t stream)
{
    const float* x_q  = (const float*)d_in[0];
    const float* x_k  = (const float*)d_in[1];
    const float* x_v  = (const float*)d_in[2];
    const float* mask = (const float*)d_in[3];
    const float* Wq   = (const float*)d_in[4];
    const float* bq   = (const float*)d_in[5];
    const float* Wk   = (const float*)d_in[6];
    const float* bk   = (const float*)d_in[7];
    const float* Wv   = (const float*)d_in[8];
    const float* bv   = (const float*)d_in[9];
    const float* Wo   = (const float*)d_in[10];
    const float* bo   = (const float*)d_in[11];
    const float* theta= (const float*)d_in[12];
    const float* phi  = (const float*)d_in[13];
    const float* Wre  = (const float*)d_in[14];
    const float* Wim  = (const float*)d_in[15];
    const float* rb   = (const float*)d_in[16];

    float* ws = (float*)d_ws;
    float*  q_ws    = ws;                       // 262144 f
    float*  k_ws    = ws + 262144;              // 262144 f
    float*  v_ws    = ws + 524288;              // 262144 f
    float2* u_ws    = (float2*)(ws + 786432);   // 262144 float2
    float*  rnn_o   = ws + 1310720;             // 262144 f

    float* out_o  = (float*)d_out;              // (2,256,512)
    float* attn_o = out_o + NB * NL * DM;       // (2,8,256,256)

    qkv_gemm<<<dim3(8, 16, 3), 256, 0, stream>>>(
        x_q, x_k, x_v, Wq, Wk, Wv, bq, bk, bv, q_ws, k_ws, v_ws);

    attn_u_kernel<<<dim3(320, NH, NB), 256, 0, stream>>>(
        q_ws, k_ws, mask, attn_o, v_ws, Wre, Wim, u_ws);

    rnn_kernel<<<dim3(1024), 256, 0, stream>>>(
        attn_o, u_ws, theta, phi, rb, rnn_o);

    out_gemm<<<dim3(8, 32), 256, 0, stream>>>(rnn_o, Wo, bo, out_o);
}

// Round 5
// 219.929 us; speedup vs baseline: 1.1714x; 1.1714x over previous
//
#include <hip/hip_runtime.h>
#include <math.h>

#define NB 2
#define NL 256
#define DM 512
#define NH 8
#define DQ 64

// ---------------------------------------------------------------------------
// K1: QKV projection GEMM. 32x64 tile, K-tile 32, thread tile 2x4.
// ---------------------------------------------------------------------------
__global__ __launch_bounds__(256) void qkv_gemm(
    const float* __restrict__ xq, const float* __restrict__ xk,
    const float* __restrict__ xv,
    const float* __restrict__ Wq, const float* __restrict__ Wk,
    const float* __restrict__ Wv,
    const float* __restrict__ bq, const float* __restrict__ bk,
    const float* __restrict__ bv,
    float* __restrict__ q, float* __restrict__ k, float* __restrict__ v)
{
    int z = blockIdx.z;
    const float* X = (z == 0) ? xq : (z == 1) ? xk : xv;
    const float* W = (z == 0) ? Wq : (z == 1) ? Wk : Wv;
    const float* bias = (z == 0) ? bq : (z == 1) ? bk : bv;
    float* O = (z == 0) ? q : (z == 1) ? k : v;

    __shared__ float As[32][33];
    __shared__ float Bs[32][68];

    int tid = threadIdx.x;
    int tx = tid & 15, ty = tid >> 4;
    int m0 = blockIdx.y * 32, n0 = blockIdx.x * 64;

    float acc[2][4] = {};

    for (int k0 = 0; k0 < 512; k0 += 32) {
        {
            int r = tid >> 3, c4 = (tid & 7) * 4;
            const float4 av = *(const float4*)(X + (m0 + r) * 512 + k0 + c4);
            As[c4 + 0][r] = av.x; As[c4 + 1][r] = av.y;
            As[c4 + 2][r] = av.z; As[c4 + 3][r] = av.w;
        }
        {
            int r = tid >> 4, c4 = (tid & 15) * 4;
            float4 b0 = *(const float4*)(W + (k0 + r) * 512 + n0 + c4);
            float4 b1 = *(const float4*)(W + (k0 + r + 16) * 512 + n0 + c4);
            *(float4*)&Bs[r][c4] = b0;
            *(float4*)&Bs[r + 16][c4] = b1;
        }
        __syncthreads();
        #pragma unroll
        for (int kk = 0; kk < 32; kk++) {
            float a0 = As[kk][ty * 2 + 0];
            float a1 = As[kk][ty * 2 + 1];
            float4 bb = *(const float4*)&Bs[kk][tx * 4];
            acc[0][0] += a0 * bb.x; acc[0][1] += a0 * bb.y;
            acc[0][2] += a0 * bb.z; acc[0][3] += a0 * bb.w;
            acc[1][0] += a1 * bb.x; acc[1][1] += a1 * bb.y;
            acc[1][2] += a1 * bb.z; acc[1][3] += a1 * bb.w;
        }
        __syncthreads();
    }

    #pragma unroll
    for (int i = 0; i < 2; i++) {
        int m = m0 + ty * 2 + i;
        int b = m >> 8, l = m & 255;
        #pragma unroll
        for (int j = 0; j < 4; j++) {
            int n = n0 + tx * 4 + j;
            int h = n >> 6, d = n & 63;
            O[((b * NH + h) * NL + l) * DQ + d] = acc[i][j] + bias[n];
        }
    }
}

// ---------------------------------------------------------------------------
// K2: fused attn softmax + u precompute. blockIdx.x<256 -> attn row, else u.
// ---------------------------------------------------------------------------
__global__ __launch_bounds__(256) void attn_u_kernel(
    const float* __restrict__ q, const float* __restrict__ k,
    const float* __restrict__ mask, float* __restrict__ attn_o,
    const float* __restrict__ v, const float* __restrict__ Wre,
    const float* __restrict__ Wim, float2* __restrict__ u)
{
    int h = blockIdx.y, b = blockIdx.z;
    int tid = threadIdx.x;
    __shared__ float smem[264];

    if (blockIdx.x < 256) {
        int qi = blockIdx.x;
        int wv = tid >> 6, lane = tid & 63;
        float* qrow = smem;
        float* wred = smem + 256;
        float* wsum = smem + 260;

        if (tid < 16)
            ((float4*)qrow)[tid] = ((const float4*)(q + ((b * NH + h) * NL + qi) * DQ))[tid];
        __syncthreads();

        const float4* kp = (const float4*)(k + ((b * NH + h) * NL + tid) * DQ);
        float acc = 0.f;
        #pragma unroll
        for (int d4 = 0; d4 < 16; d4++) {
            float4 kv = kp[d4];
            float4 qv = ((const float4*)qrow)[d4];
            acc += qv.x * kv.x + qv.y * kv.y + qv.z * kv.z + qv.w * kv.w;
        }
        acc *= 0.125f;

        float mv = mask[(b * NL + qi) * NL + tid];
        acc -= (mv == 1.0f) ? INFINITY : mv;

        float mx = acc;
        #pragma unroll
        for (int o = 32; o; o >>= 1) mx = fmaxf(mx, __shfl_xor(mx, o, 64));
        if (lane == 0) wred[wv] = mx;
        __syncthreads();
        mx = fmaxf(fmaxf(wred[0], wred[1]), fmaxf(wred[2], wred[3]));

        float e = __expf(acc - mx);
        float s = e;
        #pragma unroll
        for (int o = 32; o; o >>= 1) s += __shfl_xor(s, o, 64);
        if (lane == 0) wsum[wv] = s;
        __syncthreads();
        s = wsum[0] + wsum[1] + wsum[2] + wsum[3];

        attn_o[((b * NH + h) * NL + qi) * NL + tid] = e * __builtin_amdgcn_rcpf(s);
    } else {
        int xi = blockIdx.x - 256;          // 0..63
        int e = tid & 63, tq = tid >> 6;
        int t = xi * 4 + tq;
        float (*vrow)[64] = (float (*)[64])smem;

        const float* vp = v + ((b * NH + h) * NL + t) * DQ;
        vrow[tq][e] = vp[e];
        __syncthreads();

        const float* wr = Wre + h * 4096 + e;
        const float* wi = Wim + h * 4096 + e;
        float ar = 0.f, ai = 0.f;
        #pragma unroll
        for (int d = 0; d < 64; d++) {
            float vv = vrow[tq][d];
            ar += vv * wr[d * 64];
            ai += vv * wi[d * 64];
        }
        u[((b * NH + h) * NL + t) * DQ + e] = make_float2(ar, ai);
    }
}

// ---------------------------------------------------------------------------
// K3: EUNN recurrence, 2 state elements per lane.
// Lane lp (0..31 within half-wave) holds complex pair d = {2lp, 2lp+1}.
// A wave64 carries TWO recurrences (lanes 0-31 rec A, 32-63 rec B).
// Stage 0 (pairs (2j,2j+1)) is entirely in-lane (no shuffles):
//   na = c0*e0 + W0a*e1 ; nb = W0b*e0 + c0*e1
//   (na = h1[2lp], nb = h1[2lp+1])
// Stage 1 (pairs (2j+1, 2j+2 mod 64)):
//   z1 = new[2lp+1] = c1(lp)*nb + W1a(lp)*f1,   f1 = lane lp+1's na
//   z0 = new[2lp]   = c1(jm)*na + W1b(jm)*f2,   f2 = lane lp-1's nb, jm=lp-1
// Only 4 bpermutes per step (f1,f2 re/im), all within the 32-lane half.
// ---------------------------------------------------------------------------
__global__ __launch_bounds__(256) void rnn_kernel(
    const float* __restrict__ attn_f, const float2* __restrict__ u,
    const float* __restrict__ theta, const float* __restrict__ phi,
    const float* __restrict__ rnn_bias, float* __restrict__ rnn_out)
{
    int tid = threadIdx.x;
    int wv = tid >> 6;
    int lane = tid & 63;
    int half = lane >> 5;
    int lp = lane & 31;
    int rec = blockIdx.x * 8 + wv * 2 + half;   // 0..4095
    int qi = rec & 255, h = (rec >> 8) & 7, b = rec >> 11;

    const float* tb = theta + h * 64;   // [c][j] = [2][32]
    const float* pb = phi + h * 64;

    // stage-0 pair j = lp
    float th0 = tb[lp], ph0 = pb[lp];
    float c0 = cosf(th0), s0 = sinf(th0);
    float cp0 = cosf(ph0), sp0 = sinf(ph0);
    float W0ar = -s0 * cp0, W0ai = -s0 * sp0;   // coeff on e1 in na
    float W0br =  s0 * cp0, W0bi = -s0 * sp0;   // coeff on e0 in nb

    // stage-1 pair j = lp  (output element 2lp+1)
    float th1 = tb[32 + lp], ph1 = pb[32 + lp];
    float c1 = cosf(th1), s1 = sinf(th1);
    float W1ar = -s1 * cosf(ph1), W1ai = -s1 * sinf(ph1);   // on f1

    // stage-1 pair jm = lp-1 (output element 2lp)
    int jm = (lp + 31) & 31;
    float th1m = tb[32 + jm], ph1m = pb[32 + jm];
    float c1m = cosf(th1m), s1m = sinf(th1m);
    float W1br = s1m * cosf(ph1m), W1bi = -s1m * sinf(ph1m); // on f2

    float bias0 = rnn_bias[h * 64 + 2 * lp];
    float bias1 = rnn_bias[h * 64 + 2 * lp + 1];

    int idx_p = (lane & 32) | ((lp + 1) & 31);
    int idx_m = (lane & 32) | ((lp + 31) & 31);

    __shared__ float arow[8 * 256];
    {
        const float4* ap = (const float4*)(attn_f + (size_t)blockIdx.x * 8 * 256);
        ((float4*)arow)[tid] = ap[tid];
        ((float4*)arow)[tid + 256] = ap[tid + 256];
    }
    __syncthreads();
    const float* arc = arow + (wv * 2 + half) * 256;

    // u row: 64 float2 = 32 float4 per step; lane lp takes float4 lp
    const float4* up4 = (const float4*)(u + (size_t)((b * NH + h) * NL) * DQ) + lp;

    float e0r = 0.f, e0i = 0.f, e1r = 0.f, e1i = 0.f;
    #pragma unroll 4
    for (int t = 0; t < 256; t++) {
        float4 uu = up4[t * 32];          // u[t][2lp].re/.im, u[t][2lp+1].re/.im
        float a_t = arc[t];

        // stage 0 (in-lane)
        float na_r = c0 * e0r + (W0ar * e1r - W0ai * e1i);
        float na_i = c0 * e0i + (W0ar * e1i + W0ai * e1r);
        float nb_r = c0 * e1r + (W0br * e0r - W0bi * e0i);
        float nb_i = c0 * e1i + (W0br * e0i + W0bi * e0r);

        // neighbor fetch (within 32-lane half)
        float f1r = __shfl(na_r, idx_p, 64);   // h1[2lp+2]
        float f1i = __shfl(na_i, idx_p, 64);
        float f2r = __shfl(nb_r, idx_m, 64);   // h1[2lp-1]
        float f2i = __shfl(nb_i, idx_m, 64);

        // stage 1
        float z1r = c1 * nb_r + (W1ar * f1r - W1ai * f1i);
        float z1i = c1 * nb_i + (W1ar * f1i + W1ai * f1r);
        float z0r = c1m * na_r + (W1br * f2r - W1bi * f2i);
        float z0i = c1m * na_i + (W1br * f2i + W1bi * f2r);

        // + a_t * u_t
        z0r += a_t * uu.x; z0i += a_t * uu.y;
        z1r += a_t * uu.z; z1i += a_t * uu.w;

        // modrelu both elements
        float mm0 = z0r * z0r + z0i * z0i;
        float m0 = __builtin_amdgcn_sqrtf(mm0);
        float sc0 = fmaxf(m0 + bias0, 0.f) * __builtin_amdgcn_rcpf(m0 + 1e-5f);
        e0r = z0r * sc0; e0i = z0i * sc0;

        float mm1 = z1r * z1r + z1i * z1i;
        float m1 = __builtin_amdgcn_sqrtf(mm1);
        float sc1 = fmaxf(m1 + bias1, 0.f) * __builtin_amdgcn_rcpf(m1 + 1e-5f);
        e1r = z1r * sc1; e1i = z1i * sc1;
    }

    // real parts -> (B, L, DM) row-major
    float2 o = make_float2(e0r, e1r);
    *(float2*)&rnn_out[(size_t)(b * NL + qi) * DM + h * DQ + 2 * lp] = o;
}

// ---------------------------------------------------------------------------
// K4: output projection. 16x64 tile, K-tile 32.
// ---------------------------------------------------------------------------
__global__ __launch_bounds__(256) void out_gemm(
    const float* __restrict__ A, const float* __restrict__ W,
    const float* __restrict__ bias, float* __restrict__ C)
{
    __shared__ float As[32][17];
    __shared__ float Bs[32][68];

    int tid = threadIdx.x;
    int tx = tid & 15, ty = tid >> 4;
    int m0 = blockIdx.y * 16, n0 = blockIdx.x * 64;

    float acc[4] = {};

    for (int k0 = 0; k0 < 512; k0 += 32) {
        {
            int r = tid >> 4, c2 = (tid & 15) * 2;
            const float2 av = *(const float2*)(A + (m0 + r) * 512 + k0 + c2);
            As[c2 + 0][r] = av.x; As[c2 + 1][r] = av.y;
        }
        {
            int r = tid >> 4, c4 = (tid & 15) * 4;
            float4 b0 = *(const float4*)(W + (k0 + r) * 512 + n0 + c4);
            float4 b1 = *(const float4*)(W + (k0 + r + 16) * 512 + n0 + c4);
            *(float4*)&Bs[r][c4] = b0;
            *(float4*)&Bs[r + 16][c4] = b1;
        }
        __syncthreads();
        #pragma unroll
        for (int kk = 0; kk < 32; kk++) {
            float a = As[kk][ty];
            float4 bb = *(const float4*)&Bs[kk][tx * 4];
            acc[0] += a * bb.x; acc[1] += a * bb.y;
            acc[2] += a * bb.z; acc[3] += a * bb.w;
        }
        __syncthreads();
    }

    int m = m0 + ty;
    #pragma unroll
    for (int j = 0; j < 4; j++) {
        int n = n0 + tx * 4 + j;
        C[m * 512 + n] = acc[j] + bias[n];
    }
}

// ---------------------------------------------------------------------------
extern "C" void kernel_launch(void* const* d_in, const int* in_sizes, int n_in,
                              void* d_out, int out_size, void* d_ws, size_t ws_size,
                              hipStream_t stream)
{
    const float* x_q  = (const float*)d_in[0];
    const float* x_k  = (const float*)d_in[1];
    const float* x_v  = (const float*)d_in[2];
    const float* mask = (const float*)d_in[3];
    const float* Wq   = (const float*)d_in[4];
    const float* bq   = (const float*)d_in[5];
    const float* Wk   = (const float*)d_in[6];
    const float* bk   = (const float*)d_in[7];
    const float* Wv   = (const float*)d_in[8];
    const float* bv   = (const float*)d_in[9];
    const float* Wo   = (const float*)d_in[10];
    const float* bo   = (const float*)d_in[11];
    const float* theta= (const float*)d_in[12];
    const float* phi  = (const float*)d_in[13];
    const float* Wre  = (const float*)d_in[14];
    const float* Wim  = (const float*)d_in[15];
    const float* rb   = (const float*)d_in[16];

    float* ws = (float*)d_ws;
    float*  q_ws    = ws;                       // 262144 f
    float*  k_ws    = ws + 262144;              // 262144 f
    float*  v_ws    = ws + 524288;              // 262144 f
    float2* u_ws    = (float2*)(ws + 786432);   // 262144 float2
    float*  rnn_o   = ws + 1310720;             // 262144 f

    float* out_o  = (float*)d_out;              // (2,256,512)
    float* attn_o = out_o + NB * NL * DM;       // (2,8,256,256)

    qkv_gemm<<<dim3(8, 16, 3), 256, 0, stream>>>(
        x_q, x_k, x_v, Wq, Wk, Wv, bq, bk, bv, q_ws, k_ws, v_ws);

    attn_u_kernel<<<dim3(320, NH, NB), 256, 0, stream>>>(
        q_ws, k_ws, mask, attn_o, v_ws, Wre, Wim, u_ws);

    rnn_kernel<<<dim3(512), 256, 0, stream>>>(
        attn_o, u_ws, theta, phi, rb, rnn_o);

    out_gemm<<<dim3(8, 32), 256, 0, stream>>>(rnn_o, Wo, bo, out_o);
}

// Round 6
// 218.185 us; speedup vs baseline: 1.1808x; 1.0080x over previous
//
#include <hip/hip_runtime.h>
#include <math.h>

#define NB 2
#define NL 256
#define DM 512
#define NH 8
#define DQ 64

// ---------------------------------------------------------------------------
// K1: QKV projection GEMM. 32x64 tile, K-tile 32, thread tile 2x4.
// ---------------------------------------------------------------------------
__global__ __launch_bounds__(256) void qkv_gemm(
    const float* __restrict__ xq, const float* __restrict__ xk,
    const float* __restrict__ xv,
    const float* __restrict__ Wq, const float* __restrict__ Wk,
    const float* __restrict__ Wv,
    const float* __restrict__ bq, const float* __restrict__ bk,
    const float* __restrict__ bv,
    float* __restrict__ q, float* __restrict__ k, float* __restrict__ v)
{
    int z = blockIdx.z;
    const float* X = (z == 0) ? xq : (z == 1) ? xk : xv;
    const float* W = (z == 0) ? Wq : (z == 1) ? Wk : Wv;
    const float* bias = (z == 0) ? bq : (z == 1) ? bk : bv;
    float* O = (z == 0) ? q : (z == 1) ? k : v;

    __shared__ float As[32][33];
    __shared__ float Bs[32][68];

    int tid = threadIdx.x;
    int tx = tid & 15, ty = tid >> 4;
    int m0 = blockIdx.y * 32, n0 = blockIdx.x * 64;

    float acc[2][4] = {};

    for (int k0 = 0; k0 < 512; k0 += 32) {
        {
            int r = tid >> 3, c4 = (tid & 7) * 4;
            const float4 av = *(const float4*)(X + (m0 + r) * 512 + k0 + c4);
            As[c4 + 0][r] = av.x; As[c4 + 1][r] = av.y;
            As[c4 + 2][r] = av.z; As[c4 + 3][r] = av.w;
        }
        {
            int r = tid >> 4, c4 = (tid & 15) * 4;
            float4 b0 = *(const float4*)(W + (k0 + r) * 512 + n0 + c4);
            float4 b1 = *(const float4*)(W + (k0 + r + 16) * 512 + n0 + c4);
            *(float4*)&Bs[r][c4] = b0;
            *(float4*)&Bs[r + 16][c4] = b1;
        }
        __syncthreads();
        #pragma unroll
        for (int kk = 0; kk < 32; kk++) {
            float a0 = As[kk][ty * 2 + 0];
            float a1 = As[kk][ty * 2 + 1];
            float4 bb = *(const float4*)&Bs[kk][tx * 4];
            acc[0][0] += a0 * bb.x; acc[0][1] += a0 * bb.y;
            acc[0][2] += a0 * bb.z; acc[0][3] += a0 * bb.w;
            acc[1][0] += a1 * bb.x; acc[1][1] += a1 * bb.y;
            acc[1][2] += a1 * bb.z; acc[1][3] += a1 * bb.w;
        }
        __syncthreads();
    }

    #pragma unroll
    for (int i = 0; i < 2; i++) {
        int m = m0 + ty * 2 + i;
        int b = m >> 8, l = m & 255;
        #pragma unroll
        for (int j = 0; j < 4; j++) {
            int n = n0 + tx * 4 + j;
            int h = n >> 6, d = n & 63;
            O[((b * NH + h) * NL + l) * DQ + d] = acc[i][j] + bias[n];
        }
    }
}

// ---------------------------------------------------------------------------
// K2: fused attn softmax + u precompute. blockIdx.x<256 -> attn row, else u.
// ---------------------------------------------------------------------------
__global__ __launch_bounds__(256) void attn_u_kernel(
    const float* __restrict__ q, const float* __restrict__ k,
    const float* __restrict__ mask, float* __restrict__ attn_o,
    const float* __restrict__ v, const float* __restrict__ Wre,
    const float* __restrict__ Wim, float2* __restrict__ u)
{
    int h = blockIdx.y, b = blockIdx.z;
    int tid = threadIdx.x;
    __shared__ float smem[264];

    if (blockIdx.x < 256) {
        int qi = blockIdx.x;
        int wv = tid >> 6, lane = tid & 63;
        float* qrow = smem;
        float* wred = smem + 256;
        float* wsum = smem + 260;

        if (tid < 16)
            ((float4*)qrow)[tid] = ((const float4*)(q + ((b * NH + h) * NL + qi) * DQ))[tid];
        __syncthreads();

        const float4* kp = (const float4*)(k + ((b * NH + h) * NL + tid) * DQ);
        float acc = 0.f;
        #pragma unroll
        for (int d4 = 0; d4 < 16; d4++) {
            float4 kv = kp[d4];
            float4 qv = ((const float4*)qrow)[d4];
            acc += qv.x * kv.x + qv.y * kv.y + qv.z * kv.z + qv.w * kv.w;
        }
        acc *= 0.125f;

        float mv = mask[(b * NL + qi) * NL + tid];
        acc -= (mv == 1.0f) ? INFINITY : mv;

        float mx = acc;
        #pragma unroll
        for (int o = 32; o; o >>= 1) mx = fmaxf(mx, __shfl_xor(mx, o, 64));
        if (lane == 0) wred[wv] = mx;
        __syncthreads();
        mx = fmaxf(fmaxf(wred[0], wred[1]), fmaxf(wred[2], wred[3]));

        float e = __expf(acc - mx);
        float s = e;
        #pragma unroll
        for (int o = 32; o; o >>= 1) s += __shfl_xor(s, o, 64);
        if (lane == 0) wsum[wv] = s;
        __syncthreads();
        s = wsum[0] + wsum[1] + wsum[2] + wsum[3];

        attn_o[((b * NH + h) * NL + qi) * NL + tid] = e * __builtin_amdgcn_rcpf(s);
    } else {
        int xi = blockIdx.x - 256;          // 0..63
        int e = tid & 63, tq = tid >> 6;
        int t = xi * 4 + tq;
        float (*vrow)[64] = (float (*)[64])smem;

        const float* vp = v + ((b * NH + h) * NL + t) * DQ;
        vrow[tq][e] = vp[e];
        __syncthreads();

        const float* wr = Wre + h * 4096 + e;
        const float* wi = Wim + h * 4096 + e;
        float ar = 0.f, ai = 0.f;
        #pragma unroll
        for (int d = 0; d < 64; d++) {
            float vv = vrow[tq][d];
            ar += vv * wr[d * 64];
            ai += vv * wi[d * 64];
        }
        u[((b * NH + h) * NL + t) * DQ + e] = make_float2(ar, ai);
    }
}

// ---------------------------------------------------------------------------
// K3: EUNN recurrence, 2 state elements per lane, recurrences INTERLEAVED by
// lane parity so cross-lane exchange is a whole-wave rotate by 2 — pure-VALU
// DPP (wave_rol:1 / wave_ror:1 chained twice), no LDS-path bpermute.
//   lane i: rec = i&1, pos p = i>>1 (0..31), holds elements {2p, 2p+1}.
//   f1 (stage-1 upper neighbor, element 2p+2) = na from lane (i+2)%64
//   f2 (stage-1 lower neighbor, element 2p-1) = nb from lane (i-2)%64
//   (+2/-2 mod 64 preserves parity, and wraps 62->0 / 1->63 are exactly the
//    32-position ring wrap of each recurrence.)
// ---------------------------------------------------------------------------
__device__ __forceinline__ float rot_up2(float x) {   // lane i <- lane (i+2)%64
    int v = __builtin_amdgcn_mov_dpp(__float_as_int(x), 0x134, 0xF, 0xF, true);
    v = __builtin_amdgcn_mov_dpp(v, 0x134, 0xF, 0xF, true);
    return __int_as_float(v);
}
__device__ __forceinline__ float rot_dn2(float x) {   // lane i <- lane (i-2)%64
    int v = __builtin_amdgcn_mov_dpp(__float_as_int(x), 0x13C, 0xF, 0xF, true);
    v = __builtin_amdgcn_mov_dpp(v, 0x13C, 0xF, 0xF, true);
    return __int_as_float(v);
}

__global__ __launch_bounds__(256) void rnn_kernel(
    const float* __restrict__ attn_f, const float2* __restrict__ u,
    const float* __restrict__ theta, const float* __restrict__ phi,
    const float* __restrict__ rnn_bias, float* __restrict__ rnn_out)
{
    int tid = threadIdx.x;
    int wv = tid >> 6;
    int lane = tid & 63;
    int par = lane & 1;
    int p = lane >> 1;                          // 0..31
    int rec = blockIdx.x * 8 + wv * 2 + par;    // 0..4095
    int qi = rec & 255, h = (rec >> 8) & 7, b = rec >> 11;

    const float* tb = theta + h * 64;   // [c][j] = [2][32]
    const float* pb = phi + h * 64;

    // stage-0 pair j = p
    float th0 = tb[p], ph0 = pb[p];
    float c0 = cosf(th0), s0 = sinf(th0);
    float cp0 = cosf(ph0), sp0 = sinf(ph0);
    float W0ar = -s0 * cp0, W0ai = -s0 * sp0;   // coeff on e1 in na
    float W0br =  s0 * cp0, W0bi = -s0 * sp0;   // coeff on e0 in nb

    // stage-1 pair j = p  (output element 2p+1)
    float th1 = tb[32 + p], ph1 = pb[32 + p];
    float c1 = cosf(th1), s1 = sinf(th1);
    float W1ar = -s1 * cosf(ph1), W1ai = -s1 * sinf(ph1);   // on f1

    // stage-1 pair pm = p-1 (output element 2p)
    int pm = (p + 31) & 31;
    float th1m = tb[32 + pm], ph1m = pb[32 + pm];
    float c1m = cosf(th1m), s1m = sinf(th1m);
    float W1br = s1m * cosf(ph1m), W1bi = -s1m * sinf(ph1m); // on f2

    float bias0 = rnn_bias[h * 64 + 2 * p];
    float bias1 = rnn_bias[h * 64 + 2 * p + 1];

    __shared__ float arow[8 * 256];
    {
        const float4* ap = (const float4*)(attn_f + (size_t)blockIdx.x * 8 * 256);
        ((float4*)arow)[tid] = ap[tid];
        ((float4*)arow)[tid + 256] = ap[tid + 256];
    }
    __syncthreads();
    const float* arc = arow + (wv * 2 + par) * 256;

    // u row: 64 float2 = 32 float4 per step; lane pair (2p,2p+1) reads float4 p
    const float4* up4 = (const float4*)(u + (size_t)((b * NH + h) * NL) * DQ) + p;

    float e0r = 0.f, e0i = 0.f, e1r = 0.f, e1i = 0.f;
    #pragma unroll 8
    for (int t = 0; t < 256; t++) {
        float4 uu = up4[t * 32];          // u[t][2p].re/.im, u[t][2p+1].re/.im
        float a_t = arc[t];

        // stage 0 (in-lane)
        float na_r = c0 * e0r + (W0ar * e1r - W0ai * e1i);
        float na_i = c0 * e0i + (W0ar * e1i + W0ai * e1r);
        float nb_r = c0 * e1r + (W0br * e0r - W0bi * e0i);
        float nb_i = c0 * e1i + (W0br * e0i + W0bi * e0r);

        // neighbor exchange via DPP (pure VALU)
        float f1r = rot_up2(na_r), f1i = rot_up2(na_i);   // h1[2p+2]
        float f2r = rot_dn2(nb_r), f2i = rot_dn2(nb_i);   // h1[2p-1]

        // stage 1
        float z1r = c1 * nb_r + (W1ar * f1r - W1ai * f1i);
        float z1i = c1 * nb_i + (W1ar * f1i + W1ai * f1r);
        float z0r = c1m * na_r + (W1br * f2r - W1bi * f2i);
        float z0i = c1m * na_i + (W1br * f2i + W1bi * f2r);

        // + a_t * u_t
        z0r += a_t * uu.x; z0i += a_t * uu.y;
        z1r += a_t * uu.z; z1i += a_t * uu.w;

        // modrelu both elements
        float mm0 = z0r * z0r + z0i * z0i;
        float m0 = __builtin_amdgcn_sqrtf(mm0);
        float sc0 = fmaxf(m0 + bias0, 0.f) * __builtin_amdgcn_rcpf(m0 + 1e-5f);
        e0r = z0r * sc0; e0i = z0i * sc0;

        float mm1 = z1r * z1r + z1i * z1i;
        float m1 = __builtin_amdgcn_sqrtf(mm1);
        float sc1 = fmaxf(m1 + bias1, 0.f) * __builtin_amdgcn_rcpf(m1 + 1e-5f);
        e1r = z1r * sc1; e1i = z1i * sc1;
    }

    // real parts -> (B, L, DM) row-major
    float2 o = make_float2(e0r, e1r);
    *(float2*)&rnn_out[(size_t)(b * NL + qi) * DM + h * DQ + 2 * p] = o;
}

// ---------------------------------------------------------------------------
// K4: output projection. 16x64 tile, K-tile 32.
// ---------------------------------------------------------------------------
__global__ __launch_bounds__(256) void out_gemm(
    const float* __restrict__ A, const float* __restrict__ W,
    const float* __restrict__ bias, float* __restrict__ C)
{
    __shared__ float As[32][17];
    __shared__ float Bs[32][68];

    int tid = threadIdx.x;
    int tx = tid & 15, ty = tid >> 4;
    int m0 = blockIdx.y * 16, n0 = blockIdx.x * 64;

    float acc[4] = {};

    for (int k0 = 0; k0 < 512; k0 += 32) {
        {
            int r = tid >> 4, c2 = (tid & 15) * 2;
            const float2 av = *(const float2*)(A + (m0 + r) * 512 + k0 + c2);
            As[c2 + 0][r] = av.x; As[c2 + 1][r] = av.y;
        }
        {
            int r = tid >> 4, c4 = (tid & 15) * 4;
            float4 b0 = *(const float4*)(W + (k0 + r) * 512 + n0 + c4);
            float4 b1 = *(const float4*)(W + (k0 + r + 16) * 512 + n0 + c4);
            *(float4*)&Bs[r][c4] = b0;
            *(float4*)&Bs[r + 16][c4] = b1;
        }
        __syncthreads();
        #pragma unroll
        for (int kk = 0; kk < 32; kk++) {
            float a = As[kk][ty];
            float4 bb = *(const float4*)&Bs[kk][tx * 4];
            acc[0] += a * bb.x; acc[1] += a * bb.y;
            acc[2] += a * bb.z; acc[3] += a * bb.w;
        }
        __syncthreads();
    }

    int m = m0 + ty;
    #pragma unroll
    for (int j = 0; j < 4; j++) {
        int n = n0 + tx * 4 + j;
        C[m * 512 + n] = acc[j] + bias[n];
    }
}

// ---------------------------------------------------------------------------
extern "C" void kernel_launch(void* const* d_in, const int* in_sizes, int n_in,
                              void* d_out, int out_size, void* d_ws, size_t ws_size,
                              hipStream_t stream)
{
    const float* x_q  = (const float*)d_in[0];
    const float* x_k  = (const float*)d_in[1];
    const float* x_v  = (const float*)d_in[2];
    const float* mask = (const float*)d_in[3];
    const float* Wq   = (const float*)d_in[4];
    const float* bq   = (const float*)d_in[5];
    const float* Wk   = (const float*)d_in[6];
    const float* bk   = (const float*)d_in[7];
    const float* Wv   = (const float*)d_in[8];
    const float* bv   = (const float*)d_in[9];
    const float* Wo   = (const float*)d_in[10];
    const float* bo   = (const float*)d_in[11];
    const float* theta= (const float*)d_in[12];
    const float* phi  = (const float*)d_in[13];
    const float* Wre  = (const float*)d_in[14];
    const float* Wim  = (const float*)d_in[15];
    const float* rb   = (const float*)d_in[16];

    float* ws = (float*)d_ws;
    float*  q_ws    = ws;                       // 262144 f
    float*  k_ws    = ws + 262144;              // 262144 f
    float*  v_ws    = ws + 524288;              // 262144 f
    float2* u_ws    = (float2*)(ws + 786432);   // 262144 float2
    float*  rnn_o   = ws + 1310720;             // 262144 f

    float* out_o  = (float*)d_out;              // (2,256,512)
    float* attn_o = out_o + NB * NL * DM;       // (2,8,256,256)

    qkv_gemm<<<dim3(8, 16, 3), 256, 0, stream>>>(
        x_q, x_k, x_v, Wq, Wk, Wv, bq, bk, bv, q_ws, k_ws, v_ws);

    attn_u_kernel<<<dim3(320, NH, NB), 256, 0, stream>>>(
        q_ws, k_ws, mask, attn_o, v_ws, Wre, Wim, u_ws);

    rnn_kernel<<<dim3(512), 256, 0, stream>>>(
        attn_o, u_ws, theta, phi, rb, rnn_o);

    out_gemm<<<dim3(8, 32), 256, 0, stream>>>(rnn_o, Wo, bo, out_o);
}